// Round 3
// baseline (21712.358 us; speedup 1.0000x reference)
//
#include <hip/hip_runtime.h>
#include <hip/hip_bf16.h>

#define VOCAB 30522
#define EMB   768
#define HID   1024
#define SEQ   4096
#define NG    4096   // 4*HID gate rows
#define NWG   256    // workgroups in persistent recurrence kernel (1 per CU)
#define RT    256    // threads per recurrence workgroup (4 waves)

// ---------------------------------------------------------------------------
// Kernel 1: xg[t][r] = dot(emb[sentence[t]], w_ih[r]) + b_ih[r] + b_hh[r]
// f32 tiled GEMM, output bf16. M=SEQ, N=NG, K=EMB.
// ---------------------------------------------------------------------------
#define BM 64
#define BN 64
#define BK 16

__global__ __launch_bounds__(256) void xg_gemm(
    const int* __restrict__ sent, const float* __restrict__ emb,
    const float* __restrict__ w_ih, const float* __restrict__ b_ih,
    const float* __restrict__ b_hh, __hip_bfloat16* __restrict__ xg) {
  __shared__ float As[BK][BM + 4];
  __shared__ float Bs[BK][BN + 4];
  const int tid = threadIdx.x;
  const int n0 = blockIdx.x * BN;
  const int m0 = blockIdx.y * BM;
  const int tx = tid & 15, ty = tid >> 4;       // 16 x 16 thread grid, 4x4 per thread
  const int lr = tid >> 2;                      // 0..63 tile row for loading
  const int lk = (tid & 3) * 4;                 // 0,4,8,12 k-offset for loading

  const int arow = sent[m0 + lr];
  const float* aptr = emb + (size_t)arow * EMB + lk;
  const float* bptr = w_ih + (size_t)(n0 + lr) * EMB + lk;

  float acc[4][4] = {};

  for (int k0 = 0; k0 < EMB; k0 += BK) {
    float4 av = *(const float4*)(aptr + k0);
    float4 bv = *(const float4*)(bptr + k0);
    __syncthreads();
    As[lk + 0][lr] = av.x; As[lk + 1][lr] = av.y;
    As[lk + 2][lr] = av.z; As[lk + 3][lr] = av.w;
    Bs[lk + 0][lr] = bv.x; Bs[lk + 1][lr] = bv.y;
    Bs[lk + 2][lr] = bv.z; Bs[lk + 3][lr] = bv.w;
    __syncthreads();
#pragma unroll
    for (int k = 0; k < BK; ++k) {
      float4 a = *(const float4*)&As[k][ty * 4];
      float4 b = *(const float4*)&Bs[k][tx * 4];
      acc[0][0] = fmaf(a.x, b.x, acc[0][0]); acc[0][1] = fmaf(a.x, b.y, acc[0][1]);
      acc[0][2] = fmaf(a.x, b.z, acc[0][2]); acc[0][3] = fmaf(a.x, b.w, acc[0][3]);
      acc[1][0] = fmaf(a.y, b.x, acc[1][0]); acc[1][1] = fmaf(a.y, b.y, acc[1][1]);
      acc[1][2] = fmaf(a.y, b.z, acc[1][2]); acc[1][3] = fmaf(a.y, b.w, acc[1][3]);
      acc[2][0] = fmaf(a.z, b.x, acc[2][0]); acc[2][1] = fmaf(a.z, b.y, acc[2][1]);
      acc[2][2] = fmaf(a.z, b.z, acc[2][2]); acc[2][3] = fmaf(a.z, b.w, acc[2][3]);
      acc[3][0] = fmaf(a.w, b.x, acc[3][0]); acc[3][1] = fmaf(a.w, b.y, acc[3][1]);
      acc[3][2] = fmaf(a.w, b.z, acc[3][2]); acc[3][3] = fmaf(a.w, b.w, acc[3][3]);
    }
  }

#pragma unroll
  for (int i = 0; i < 4; ++i) {
    int gm = m0 + ty * 4 + i;
#pragma unroll
    for (int j = 0; j < 4; ++j) {
      int gn = n0 + tx * 4 + j;
      float v = acc[i][j] + b_ih[gn] + b_hh[gn];
      xg[(size_t)gm * NG + gn] = __float2bfloat16(v);
    }
  }
}

// ---------------------------------------------------------------------------
// Kernel 2: persistent LSTM recurrence, tag-in-word sync, weights in VGPRs.
// 256 WGs x 256 threads (1 WG/CU). Wave wv owns h-index hi = 4*wg + wv
// (4 gate rows). Lane: rg = lane>>4 -> gate q; cc = lane&15 -> k-chunk.
// Each lane keeps 32 float2 of w_hh in VGPRs (64 regs) - zero per-step
// weight memory traffic. h published as (epoch<<32 | f32 bits) 8B relaxed
// agent atomics, double-buffered (race-free: tag t+1 can only appear after
// every WG fully staged tag t; staging precedes publish via barrier+datadep).
// ---------------------------------------------------------------------------
__global__ __launch_bounds__(RT) void lstm_rec(
    const float* __restrict__ w_hh, const __hip_bfloat16* __restrict__ xg,
    unsigned long long* __restrict__ slots) {
  __shared__ float hl[2][HID];   // staged h, double-buffered (8 KB)

  const int tid  = threadIdx.x;
  const int wg   = blockIdx.x;
  const int lane = tid & 63;
  const int wv   = tid >> 6;     // wave 0..3
  const int rg   = lane >> 4;    // gate q = rg (i,f,g,o)
  const int cc   = lane & 15;    // k-chunk 0..15
  const int hi   = wg * 4 + wv;              // owned h index
  const int r    = rg * HID + hi;            // gate row in [0,4096)

  // --- load this lane's 64 w_hh weights into VGPRs (f32, exact) ---
  // pairs p = cc + 16*j, j = 0..31  (columns 2p, 2p+1)
  float2 w2[32];
  const float* wr = w_hh + (size_t)r * HID;
#pragma unroll
  for (int j = 0; j < 32; ++j)
    w2[j] = *(const float2*)(wr + 2 * (cc + 16 * j));

  float c = 0.f;
  const int sbase = 4 * tid;     // this thread's 4 slots

  for (int t = 0; t < SEQ; ++t) {
    // prefetch xg for my row (latency hides under the poll); cc==0 lanes use it
    float xgv = __bfloat162float(xg[(size_t)t * NG + r]);

    // poll my 4 slots until tag == t, then stage values into LDS
    const unsigned long long want = (unsigned long long)t;
    unsigned long long* sb = slots + ((t & 1) << 10);
    unsigned long long v0, v1, v2, v3;
    for (;;) {
      v0 = __hip_atomic_load(sb + sbase + 0, __ATOMIC_RELAXED, __HIP_MEMORY_SCOPE_AGENT);
      v1 = __hip_atomic_load(sb + sbase + 1, __ATOMIC_RELAXED, __HIP_MEMORY_SCOPE_AGENT);
      v2 = __hip_atomic_load(sb + sbase + 2, __ATOMIC_RELAXED, __HIP_MEMORY_SCOPE_AGENT);
      v3 = __hip_atomic_load(sb + sbase + 3, __ATOMIC_RELAXED, __HIP_MEMORY_SCOPE_AGENT);
      if (((v0 >> 32) == want) & ((v1 >> 32) == want) &
          ((v2 >> 32) == want) & ((v3 >> 32) == want)) break;
      __builtin_amdgcn_s_sleep(1);
    }
    float* hb = hl[t & 1];
    hb[sbase + 0] = __uint_as_float((unsigned)v0);
    hb[sbase + 1] = __uint_as_float((unsigned)v1);
    hb[sbase + 2] = __uint_as_float((unsigned)v2);
    hb[sbase + 3] = __uint_as_float((unsigned)v3);
    __syncthreads();

    // dot: row r x h; pairs p = cc + 16*j  (conflict-free float2 LDS reads)
    float acc = 0.f;
#pragma unroll
    for (int j = 0; j < 32; ++j) {
      float2 h2 = *(const float2*)&hb[2 * (cc + 16 * j)];
      acc = fmaf(w2[j].x, h2.x, acc);
      acc = fmaf(w2[j].y, h2.y, acc);
    }
    // reduce over the 16 k-chunks within each gate group
    acc += __shfl_down(acc, 8, 16);
    acc += __shfl_down(acc, 4, 16);
    acc += __shfl_down(acc, 2, 16);
    acc += __shfl_down(acc, 1, 16);
    acc += xgv;   // cc==0 lanes hold the full gate pre-activation

    // gather f,g,o to lane 0 (i-gate lane)
    float vf = __shfl(acc, 16);
    float vg = __shfl(acc, 32);
    float vo = __shfl(acc, 48);

    if (lane == 0) {
      float i_ = 1.f / (1.f + __expf(-acc));
      float f_ = 1.f / (1.f + __expf(-vf));
      float g_ = tanhf(vg);
      float o_ = 1.f / (1.f + __expf(-vo));
      c = fmaf(f_, c, i_ * g_);
      float hn = o_ * tanhf(c);
      unsigned long long pv =
          ((unsigned long long)(unsigned)(t + 1) << 32) |
          (unsigned long long)__float_as_uint(hn);
      __hip_atomic_store(slots + (((t + 1) & 1) << 10) + hi, pv,
                         __ATOMIC_RELAXED, __HIP_MEMORY_SCOPE_AGENT);
    }
    // no trailing barrier needed: next staging targets the other LDS buffer,
    // and tag t+2 cannot appear before every WG fully consumed tag t.
  }
}

// ---------------------------------------------------------------------------
// Kernel 3: y = h_T @ w_out.T + b_out ; log_softmax. h_T = slots buf0 values.
// ---------------------------------------------------------------------------
__global__ __launch_bounds__(256) void head_kernel(
    const unsigned long long* __restrict__ hslots, const float* __restrict__ w_out,
    const float* __restrict__ b_out, float* __restrict__ out) {
  __shared__ float s0[256], s1[256];
  const int tid = threadIdx.x;
  float p0 = 0.f, p1 = 0.f;
  for (int i = tid; i < HID; i += 256) {
    float hv = __uint_as_float((unsigned)hslots[i]);
    p0 = fmaf(hv, w_out[i], p0);
    p1 = fmaf(hv, w_out[HID + i], p1);
  }
  s0[tid] = p0; s1[tid] = p1;
  __syncthreads();
  for (int off = 128; off; off >>= 1) {
    if (tid < off) { s0[tid] += s0[tid + off]; s1[tid] += s1[tid + off]; }
    __syncthreads();
  }
  if (tid == 0) {
    float y0 = s0[0] + b_out[0], y1 = s1[0] + b_out[1];
    float m = fmaxf(y0, y1);
    float lse = m + logf(expf(y0 - m) + expf(y1 - m));
    out[0] = y0 - lse;
    out[1] = y1 - lse;
  }
}

// ---------------------------------------------------------------------------
extern "C" void kernel_launch(void* const* d_in, const int* in_sizes, int n_in,
                              void* d_out, int out_size, void* d_ws, size_t ws_size,
                              hipStream_t stream) {
  const int*   sent  = (const int*)d_in[0];
  const float* emb   = (const float*)d_in[1];
  const float* w_ih  = (const float*)d_in[2];
  const float* w_hh  = (const float*)d_in[3];
  const float* b_ih  = (const float*)d_in[4];
  const float* b_hh  = (const float*)d_in[5];
  const float* w_out = (const float*)d_in[6];
  const float* b_out = (const float*)d_in[7];
  float* out = (float*)d_out;

  // workspace layout
  unsigned long long* slots = (unsigned long long*)d_ws;         // 2*1024*8 = 16KB
  __hip_bfloat16* xg = (__hip_bfloat16*)((char*)d_ws + 16384);   // SEQ*NG bf16

  // zero slot tags (= h_0 state at epoch 0) every launch/replay
  hipMemsetAsync(d_ws, 0, 16384, stream);

  // xg GEMM
  dim3 ggrid(NG / BN, SEQ / BM);
  xg_gemm<<<ggrid, 256, 0, stream>>>(sent, emb, w_ih, b_ih, b_hh, xg);

  // persistent recurrence (256 WGs, 1 per CU, all co-resident)
  lstm_rec<<<NWG, RT, 0, stream>>>(w_hh, xg, slots);

  // head: final h tagged 4096 lives in slots buffer 0
  head_kernel<<<1, 256, 0, stream>>>(slots, w_out, b_out, out);
}

// Round 4
// 14273.338 us; speedup vs baseline: 1.5212x; 1.5212x over previous
//
#include <hip/hip_runtime.h>
#include <hip/hip_bf16.h>

#define VOCAB 30522
#define EMB   768
#define HID   1024
#define SEQ   4096
#define NG    4096   // 4*HID gate rows
#define NWG   64     // workgroups in persistent recurrence kernel
#define RT    512    // threads per recurrence workgroup (8 waves)

// ---------------------------------------------------------------------------
// Kernel 1: xg[t][r] = dot(emb[sentence[t]], w_ih[r]) + b_ih[r] + b_hh[r]
// f32 tiled GEMM, output bf16. M=SEQ, N=NG, K=EMB.
// ---------------------------------------------------------------------------
#define BM 64
#define BN 64
#define BK 16

__global__ __launch_bounds__(256) void xg_gemm(
    const int* __restrict__ sent, const float* __restrict__ emb,
    const float* __restrict__ w_ih, const float* __restrict__ b_ih,
    const float* __restrict__ b_hh, __hip_bfloat16* __restrict__ xg) {
  __shared__ float As[BK][BM + 4];
  __shared__ float Bs[BK][BN + 4];
  const int tid = threadIdx.x;
  const int n0 = blockIdx.x * BN;
  const int m0 = blockIdx.y * BM;
  const int tx = tid & 15, ty = tid >> 4;       // 16 x 16 thread grid, 4x4 per thread
  const int lr = tid >> 2;                      // 0..63 tile row for loading
  const int lk = (tid & 3) * 4;                 // 0,4,8,12 k-offset for loading

  const int arow = sent[m0 + lr];
  const float* aptr = emb + (size_t)arow * EMB + lk;
  const float* bptr = w_ih + (size_t)(n0 + lr) * EMB + lk;

  float acc[4][4] = {};

  for (int k0 = 0; k0 < EMB; k0 += BK) {
    float4 av = *(const float4*)(aptr + k0);
    float4 bv = *(const float4*)(bptr + k0);
    __syncthreads();
    As[lk + 0][lr] = av.x; As[lk + 1][lr] = av.y;
    As[lk + 2][lr] = av.z; As[lk + 3][lr] = av.w;
    Bs[lk + 0][lr] = bv.x; Bs[lk + 1][lr] = bv.y;
    Bs[lk + 2][lr] = bv.z; Bs[lk + 3][lr] = bv.w;
    __syncthreads();
#pragma unroll
    for (int k = 0; k < BK; ++k) {
      float4 a = *(const float4*)&As[k][ty * 4];
      float4 b = *(const float4*)&Bs[k][tx * 4];
      acc[0][0] = fmaf(a.x, b.x, acc[0][0]); acc[0][1] = fmaf(a.x, b.y, acc[0][1]);
      acc[0][2] = fmaf(a.x, b.z, acc[0][2]); acc[0][3] = fmaf(a.x, b.w, acc[0][3]);
      acc[1][0] = fmaf(a.y, b.x, acc[1][0]); acc[1][1] = fmaf(a.y, b.y, acc[1][1]);
      acc[1][2] = fmaf(a.y, b.z, acc[1][2]); acc[1][3] = fmaf(a.y, b.w, acc[1][3]);
      acc[2][0] = fmaf(a.z, b.x, acc[2][0]); acc[2][1] = fmaf(a.z, b.y, acc[2][1]);
      acc[2][2] = fmaf(a.z, b.z, acc[2][2]); acc[2][3] = fmaf(a.z, b.w, acc[2][3]);
      acc[3][0] = fmaf(a.w, b.x, acc[3][0]); acc[3][1] = fmaf(a.w, b.y, acc[3][1]);
      acc[3][2] = fmaf(a.w, b.z, acc[3][2]); acc[3][3] = fmaf(a.w, b.w, acc[3][3]);
    }
  }

#pragma unroll
  for (int i = 0; i < 4; ++i) {
    int gm = m0 + ty * 4 + i;
#pragma unroll
    for (int j = 0; j < 4; ++j) {
      int gn = n0 + tx * 4 + j;
      float v = acc[i][j] + b_ih[gn] + b_hh[gn];
      xg[(size_t)gm * NG + gn] = __float2bfloat16(v);
    }
  }
}

// ---------------------------------------------------------------------------
// Kernel 2: persistent LSTM recurrence, tag-in-word sync, VGPR-pinned weights.
// 64 WGs x 512 threads. Wave wv owns h-indices {16*wg+2*wv, +1}.
// Row set per wave: s = 2q+m -> gate q (i,f,g,o), h-offset m.
// Lane (=c) owns column pairs p = c + 64k, k=0..7 (16 columns) for all 8 rows
// -> 128 f32 weights in VGPRs, opaque-ified so the compiler CANNOT
// rematerialize the global loads inside the loop (rounds 2/3 failure mode).
// Dot: 128 fma into acc[8]; 6-level shfl_xor butterfly -> every lane holds
// all 8 gate sums; lanes 0,1 finalize their h-index and publish.
// h published as (epoch<<32 | f32 bits) 8B relaxed agent atomics,
// double-buffered; per-thread 2-slot poll (proven race-free; tag t+2 cannot
// appear before every WG fully consumed tag t).
// ---------------------------------------------------------------------------
__global__ __launch_bounds__(RT, 2) void lstm_rec(
    const float* __restrict__ w_hh, const __hip_bfloat16* __restrict__ xg,
    unsigned long long* __restrict__ slots) {
  __shared__ float hl[2][HID];   // staged h, double-buffered (8 KB)

  const int tid  = threadIdx.x;
  const int wg   = blockIdx.x;
  const int lane = tid & 63;
  const int wv   = tid >> 6;     // wave 0..7
  const int c    = lane;         // column-chunk id 0..63

  // --- one-time: load this lane's 128 w_hh weights into VGPRs (f32, exact) ---
  float2 w2[8][8];
#pragma unroll
  for (int s = 0; s < 8; ++s) {
    const int q = s >> 1, m = s & 1;
    const int gr = q * HID + wg * 16 + 2 * wv + m;
    const float* wr = w_hh + (size_t)gr * HID;
#pragma unroll
    for (int k = 0; k < 8; ++k)
      w2[s][k] = *(const float2*)(wr + 2 * (c + 64 * k));
  }
  // pin: make values opaque so rematerialization of the loads is impossible
#pragma unroll
  for (int s = 0; s < 8; ++s)
#pragma unroll
    for (int k = 0; k < 8; ++k)
      asm volatile("" : "+v"(w2[s][k].x), "+v"(w2[s][k].y));

  float cst = 0.f;               // cell state (meaningful on lanes 0,1)
  const int sbase = 2 * tid;     // this thread's 2 slots

  for (int t = 0; t < SEQ; ++t) {
    // xg prefetch for finalizing lanes (hides under the poll)
    float xq0 = 0.f, xq1 = 0.f, xq2 = 0.f, xq3 = 0.f;
    if (lane < 2) {
      const int hi = wg * 16 + 2 * wv + lane;
      const __hip_bfloat16* xr = xg + (size_t)t * NG + hi;
      xq0 = __bfloat162float(xr[0]);
      xq1 = __bfloat162float(xr[HID]);
      xq2 = __bfloat162float(xr[2 * HID]);
      xq3 = __bfloat162float(xr[3 * HID]);
    }

    // poll my 2 slots until tag == t, then stage values into LDS
    const unsigned long long want = (unsigned long long)t;
    unsigned long long* sb = slots + ((t & 1) << 10);
    unsigned long long v0, v1;
    for (;;) {
      v0 = __hip_atomic_load(sb + sbase,     __ATOMIC_RELAXED, __HIP_MEMORY_SCOPE_AGENT);
      v1 = __hip_atomic_load(sb + sbase + 1, __ATOMIC_RELAXED, __HIP_MEMORY_SCOPE_AGENT);
      if (((v0 >> 32) == want) & ((v1 >> 32) == want)) break;
      __builtin_amdgcn_s_sleep(1);
    }
    float* hb = hl[t & 1];
    hb[sbase]     = __uint_as_float((unsigned)v0);
    hb[sbase + 1] = __uint_as_float((unsigned)v1);
    __syncthreads();

    // h chunk into registers (read once, used for all 8 rows)
    float2 h2[8];
#pragma unroll
    for (int k = 0; k < 8; ++k)
      h2[k] = *(const float2*)&hb[2 * (c + 64 * k)];

    float acc[8];
#pragma unroll
    for (int s = 0; s < 8; ++s) {
      float a = 0.f;
#pragma unroll
      for (int k = 0; k < 8; ++k) {
        a = fmaf(w2[s][k].x, h2[k].x, a);
        a = fmaf(w2[s][k].y, h2[k].y, a);
      }
      acc[s] = a;
    }
    // full-wave butterfly: every lane ends with all 8 totals
#pragma unroll
    for (int lvl = 1; lvl < 64; lvl <<= 1)
#pragma unroll
      for (int s = 0; s < 8; ++s)
        acc[s] += __shfl_xor(acc[s], lvl, 64);

    if (lane < 2) {
      float i_ = 1.f / (1.f + __expf(-(acc[0 + lane] + xq0)));
      float f_ = 1.f / (1.f + __expf(-(acc[2 + lane] + xq1)));
      float g_ = tanhf(acc[4 + lane] + xq2);
      float o_ = 1.f / (1.f + __expf(-(acc[6 + lane] + xq3)));
      cst = fmaf(f_, cst, i_ * g_);
      float hn = o_ * tanhf(cst);
      const int hi = wg * 16 + 2 * wv + lane;
      unsigned long long pv =
          ((unsigned long long)(unsigned)(t + 1) << 32) |
          (unsigned long long)__float_as_uint(hn);
      __hip_atomic_store(slots + (((t + 1) & 1) << 10) + hi, pv,
                         __ATOMIC_RELAXED, __HIP_MEMORY_SCOPE_AGENT);
    }
    // no trailing barrier: next staging targets the other LDS buffer, and
    // tag t+2 cannot appear before every WG fully consumed tag t.
  }
}

// ---------------------------------------------------------------------------
// Kernel 3: y = h_T @ w_out.T + b_out ; log_softmax. h_T = slots buf0 values.
// ---------------------------------------------------------------------------
__global__ __launch_bounds__(256) void head_kernel(
    const unsigned long long* __restrict__ hslots, const float* __restrict__ w_out,
    const float* __restrict__ b_out, float* __restrict__ out) {
  __shared__ float s0[256], s1[256];
  const int tid = threadIdx.x;
  float p0 = 0.f, p1 = 0.f;
  for (int i = tid; i < HID; i += 256) {
    float hv = __uint_as_float((unsigned)hslots[i]);
    p0 = fmaf(hv, w_out[i], p0);
    p1 = fmaf(hv, w_out[HID + i], p1);
  }
  s0[tid] = p0; s1[tid] = p1;
  __syncthreads();
  for (int off = 128; off; off >>= 1) {
    if (tid < off) { s0[tid] += s0[tid + off]; s1[tid] += s1[tid + off]; }
    __syncthreads();
  }
  if (tid == 0) {
    float y0 = s0[0] + b_out[0], y1 = s1[0] + b_out[1];
    float m = fmaxf(y0, y1);
    float lse = m + logf(expf(y0 - m) + expf(y1 - m));
    out[0] = y0 - lse;
    out[1] = y1 - lse;
  }
}

// ---------------------------------------------------------------------------
extern "C" void kernel_launch(void* const* d_in, const int* in_sizes, int n_in,
                              void* d_out, int out_size, void* d_ws, size_t ws_size,
                              hipStream_t stream) {
  const int*   sent  = (const int*)d_in[0];
  const float* emb   = (const float*)d_in[1];
  const float* w_ih  = (const float*)d_in[2];
  const float* w_hh  = (const float*)d_in[3];
  const float* b_ih  = (const float*)d_in[4];
  const float* b_hh  = (const float*)d_in[5];
  const float* w_out = (const float*)d_in[6];
  const float* b_out = (const float*)d_in[7];
  float* out = (float*)d_out;

  // workspace layout
  unsigned long long* slots = (unsigned long long*)d_ws;         // 2*1024*8 = 16KB
  __hip_bfloat16* xg = (__hip_bfloat16*)((char*)d_ws + 16384);   // SEQ*NG bf16

  // zero slot tags (= h_0 state at epoch 0) every launch/replay
  hipMemsetAsync(d_ws, 0, 16384, stream);

  // xg GEMM
  dim3 ggrid(NG / BN, SEQ / BM);
  xg_gemm<<<ggrid, 256, 0, stream>>>(sent, emb, w_ih, b_ih, b_hh, xg);

  // persistent recurrence (64 WGs << 256 CUs -> always co-resident)
  lstm_rec<<<NWG, RT, 0, stream>>>(w_hh, xg, slots);

  // head: final h tagged 4096 lives in slots buffer 0
  head_kernel<<<1, 256, 0, stream>>>(slots, w_out, b_out, out);
}

// Round 5
// 7674.747 us; speedup vs baseline: 2.8291x; 1.8598x over previous
//
#include <hip/hip_runtime.h>
#include <hip/hip_bf16.h>

#define VOCAB 30522
#define EMB   768
#define HID   1024
#define SEQ   4096
#define NG    4096   // 4*HID gate rows
#define NWG   64     // workgroups in persistent recurrence kernel
#define RT    512    // threads per recurrence workgroup (8 waves)

static __device__ __forceinline__ unsigned short f32_to_bf16(float f) {
  unsigned u = __float_as_uint(f);
  u = (u + 0x7fffu + ((u >> 16) & 1u)) >> 16;   // round-to-nearest-even
  return (unsigned short)u;
}

static __device__ __forceinline__ float tanh_fast(float x) {
  x = fminf(fmaxf(x, -15.f), 15.f);
  float e = __expf(2.f * x);
  return (e - 1.f) / (e + 1.f);
}

// ---------------------------------------------------------------------------
// Kernel 1: xg[t][r] = dot(emb[sentence[t]], w_ih[r]) + b_ih[r] + b_hh[r]
// f32 tiled GEMM, output bf16. M=SEQ, N=NG, K=EMB.
// ---------------------------------------------------------------------------
#define BM 64
#define BN 64
#define BK 16

__global__ __launch_bounds__(256) void xg_gemm(
    const int* __restrict__ sent, const float* __restrict__ emb,
    const float* __restrict__ w_ih, const float* __restrict__ b_ih,
    const float* __restrict__ b_hh, __hip_bfloat16* __restrict__ xg) {
  __shared__ float As[BK][BM + 4];
  __shared__ float Bs[BK][BN + 4];
  const int tid = threadIdx.x;
  const int n0 = blockIdx.x * BN;
  const int m0 = blockIdx.y * BM;
  const int tx = tid & 15, ty = tid >> 4;       // 16 x 16 thread grid, 4x4 per thread
  const int lr = tid >> 2;                      // 0..63 tile row for loading
  const int lk = (tid & 3) * 4;                 // 0,4,8,12 k-offset for loading

  const int arow = sent[m0 + lr];
  const float* aptr = emb + (size_t)arow * EMB + lk;
  const float* bptr = w_ih + (size_t)(n0 + lr) * EMB + lk;

  float acc[4][4] = {};

  for (int k0 = 0; k0 < EMB; k0 += BK) {
    float4 av = *(const float4*)(aptr + k0);
    float4 bv = *(const float4*)(bptr + k0);
    __syncthreads();
    As[lk + 0][lr] = av.x; As[lk + 1][lr] = av.y;
    As[lk + 2][lr] = av.z; As[lk + 3][lr] = av.w;
    Bs[lk + 0][lr] = bv.x; Bs[lk + 1][lr] = bv.y;
    Bs[lk + 2][lr] = bv.z; Bs[lk + 3][lr] = bv.w;
    __syncthreads();
#pragma unroll
    for (int k = 0; k < BK; ++k) {
      float4 a = *(const float4*)&As[k][ty * 4];
      float4 b = *(const float4*)&Bs[k][tx * 4];
      acc[0][0] = fmaf(a.x, b.x, acc[0][0]); acc[0][1] = fmaf(a.x, b.y, acc[0][1]);
      acc[0][2] = fmaf(a.x, b.z, acc[0][2]); acc[0][3] = fmaf(a.x, b.w, acc[0][3]);
      acc[1][0] = fmaf(a.y, b.x, acc[1][0]); acc[1][1] = fmaf(a.y, b.y, acc[1][1]);
      acc[1][2] = fmaf(a.y, b.z, acc[1][2]); acc[1][3] = fmaf(a.y, b.w, acc[1][3]);
      acc[2][0] = fmaf(a.z, b.x, acc[2][0]); acc[2][1] = fmaf(a.z, b.y, acc[2][1]);
      acc[2][2] = fmaf(a.z, b.z, acc[2][2]); acc[2][3] = fmaf(a.z, b.w, acc[2][3]);
      acc[3][0] = fmaf(a.w, b.x, acc[3][0]); acc[3][1] = fmaf(a.w, b.y, acc[3][1]);
      acc[3][2] = fmaf(a.w, b.z, acc[3][2]); acc[3][3] = fmaf(a.w, b.w, acc[3][3]);
    }
  }

#pragma unroll
  for (int i = 0; i < 4; ++i) {
    int gm = m0 + ty * 4 + i;
#pragma unroll
    for (int j = 0; j < 4; ++j) {
      int gn = n0 + tx * 4 + j;
      float v = acc[i][j] + b_ih[gn] + b_hh[gn];
      xg[(size_t)gm * NG + gn] = __float2bfloat16(v);
    }
  }
}

// ---------------------------------------------------------------------------
// Kernel 2: persistent LSTM recurrence.
// 64 WGs x 512 threads. Wave wv owns h pair pw = wg*8+wv (h indices 2pw,2pw+1)
// and their 8 gate rows s = 2q+m (q = gate, m = which h).
// Weights: bf16 pairs packed in 64 u32 VGPRs per lane (lane c owns packed
// column-pairs c+64k, k=0..7, for all 8 rows), asm-pinned, launch_bounds(,1)
// so the allocator has no occupancy incentive to spill (rounds 2-4 failure).
// h published as ONE 8B word per wave: (tag32 << 32) | bf16(h1)<<16 | bf16(h0),
// relaxed agent-scope atomic, double-buffered 512-word slot arrays. Each
// thread polls exactly one word (tag==t), stages the packed payload to LDS.
// Race-free: tag t+2 cannot appear in a slot before every WG has fully
// consumed (staged + barrier) tag t.
// ---------------------------------------------------------------------------
__global__ __launch_bounds__(RT, 1) void lstm_rec(
    const float* __restrict__ w_hh, const __hip_bfloat16* __restrict__ xg,
    unsigned long long* __restrict__ slots) {
  __shared__ unsigned hl[2][512];   // staged packed-bf16 h pairs (4 KB)

  const int tid  = threadIdx.x;
  const int wg   = blockIdx.x;
  const int lane = tid & 63;
  const int wv   = tid >> 6;     // wave 0..7
  const int c    = lane;         // column-pair chunk 0..63

  // --- one-time: load + pack this lane's 128 w_hh weights into 64 u32 ---
  unsigned wp[8][8];
#pragma unroll
  for (int s = 0; s < 8; ++s) {
    const int q = s >> 1, m = s & 1;
    const int gr = q * HID + wg * 16 + 2 * wv + m;
    const float* wr = w_hh + (size_t)gr * HID;
#pragma unroll
    for (int k = 0; k < 8; ++k) {
      float2 wv2 = *(const float2*)(wr + 2 * (c + 64 * k));
      wp[s][k] = ((unsigned)f32_to_bf16(wv2.y) << 16) | (unsigned)f32_to_bf16(wv2.x);
    }
  }
  // pin: opaque u32 values -> rematerialization impossible, spill unattractive
#pragma unroll
  for (int s = 0; s < 8; ++s)
#pragma unroll
    for (int k = 0; k < 8; ++k)
      asm volatile("" : "+v"(wp[s][k]));

  float cst = 0.f;               // cell state (meaningful on lanes 0,1)

  for (int t = 0; t < SEQ; ++t) {
    // xg prefetch for finalizing lanes (hides under the poll)
    float xq0 = 0.f, xq1 = 0.f, xq2 = 0.f, xq3 = 0.f;
    if (lane < 2) {
      const int hi = wg * 16 + 2 * wv + lane;
      const __hip_bfloat16* xr = xg + (size_t)t * NG + hi;
      xq0 = __bfloat162float(xr[0]);
      xq1 = __bfloat162float(xr[HID]);
      xq2 = __bfloat162float(xr[2 * HID]);
      xq3 = __bfloat162float(xr[3 * HID]);
    }

    // poll my single slot word until tag == t, stage payload into LDS
    const unsigned long long want = (unsigned long long)t;
    unsigned long long* sb = slots + ((t & 1) << 9);
    unsigned long long v;
    for (;;) {
      v = __hip_atomic_load(sb + tid, __ATOMIC_RELAXED, __HIP_MEMORY_SCOPE_AGENT);
      if ((v >> 32) == want) break;
      __builtin_amdgcn_s_sleep(1);
    }
    hl[t & 1][tid] = (unsigned)v;
    __syncthreads();

    // unpack my h chunk once (8 words -> 16 f32), reuse for all 8 rows
    const unsigned* hb = hl[t & 1];
    float hx[8], hy[8];
#pragma unroll
    for (int k = 0; k < 8; ++k) {
      unsigned hw = hb[c + 64 * k];
      hx[k] = __uint_as_float(hw << 16);
      hy[k] = __uint_as_float(hw & 0xffff0000u);
    }

    float acc[8];
#pragma unroll
    for (int s = 0; s < 8; ++s) {
      float a = 0.f;
#pragma unroll
      for (int k = 0; k < 8; ++k) {
        unsigned w = wp[s][k];
        a = fmaf(__uint_as_float(w << 16),          hx[k], a);
        a = fmaf(__uint_as_float(w & 0xffff0000u),  hy[k], a);
      }
      acc[s] = a;
    }

    // folding tree: 8 partial sums x 64 lanes -> lane L holds S_{L&7}
    // level M in {1,2,4}: a[j] = ((lane&M)?a[2j+1]:a[2j]) + shfl_xor(other, M)
#pragma unroll
    for (int M = 1, n = 8; M <= 4; M <<= 1, n >>= 1) {
#pragma unroll
      for (int j = 0; j < 4; ++j) {
        if (j < (n >> 1)) {
          float u  = (lane & M) ? acc[2 * j + 1] : acc[2 * j];
          float u2 = (lane & M) ? acc[2 * j]     : acc[2 * j + 1];
          acc[j] = u + __shfl_xor(u2, M, 64);
        }
      }
    }
    float r = acc[0];
    r += __shfl_xor(r, 8, 64);
    r += __shfl_xor(r, 16, 64);
    r += __shfl_xor(r, 32, 64);
    // r at lane L == full gate sum for s = L&7

    // lanes 0,1 (m = lane) need s = {m, 2+m, 4+m, 6+m}
    float gf = __shfl(r, 2 + lane, 64);
    float gg = __shfl(r, 4 + lane, 64);
    float go = __shfl(r, 6 + lane, 64);

    float hn = 0.f;
    if (lane < 2) {
      float i_ = 1.f / (1.f + __expf(-(r  + xq0)));
      float f_ = 1.f / (1.f + __expf(-(gf + xq1)));
      float g_ = tanh_fast(gg + xq2);
      float o_ = 1.f / (1.f + __expf(-(go + xq3)));
      cst = fmaf(f_, cst, i_ * g_);
      hn = o_ * tanh_fast(cst);
    }
    float hn1 = __shfl(hn, 1, 64);
    if (lane == 0) {
      unsigned payload = ((unsigned)f32_to_bf16(hn1) << 16) | (unsigned)f32_to_bf16(hn);
      unsigned long long pv =
          ((unsigned long long)(unsigned)(t + 1) << 32) | (unsigned long long)payload;
      __hip_atomic_store(slots + (((t + 1) & 1) << 9) + (wg * 8 + wv), pv,
                         __ATOMIC_RELAXED, __HIP_MEMORY_SCOPE_AGENT);
    }
    // no trailing barrier: next staging targets the other LDS buffer, and
    // tag t+2 cannot appear before every WG fully consumed tag t.
  }
}

// ---------------------------------------------------------------------------
// Kernel 3: y = h_T @ w_out.T + b_out ; log_softmax. h_T = slots buf0 packed.
// ---------------------------------------------------------------------------
__global__ __launch_bounds__(256) void head_kernel(
    const unsigned long long* __restrict__ hslots, const float* __restrict__ w_out,
    const float* __restrict__ b_out, float* __restrict__ out) {
  __shared__ float s0[256], s1[256];
  const int tid = threadIdx.x;
  float p0 = 0.f, p1 = 0.f;
  for (int w = tid; w < 512; w += 256) {
    unsigned pw = (unsigned)hslots[w];
    float h0 = __uint_as_float(pw << 16);
    float h1 = __uint_as_float(pw & 0xffff0000u);
    p0 = fmaf(h0, w_out[2 * w], fmaf(h1, w_out[2 * w + 1], p0));
    p1 = fmaf(h0, w_out[HID + 2 * w], fmaf(h1, w_out[HID + 2 * w + 1], p1));
  }
  s0[tid] = p0; s1[tid] = p1;
  __syncthreads();
  for (int off = 128; off; off >>= 1) {
    if (tid < off) { s0[tid] += s0[tid + off]; s1[tid] += s1[tid + off]; }
    __syncthreads();
  }
  if (tid == 0) {
    float y0 = s0[0] + b_out[0], y1 = s1[0] + b_out[1];
    float m = fmaxf(y0, y1);
    float lse = m + logf(expf(y0 - m) + expf(y1 - m));
    out[0] = y0 - lse;
    out[1] = y1 - lse;
  }
}

// ---------------------------------------------------------------------------
extern "C" void kernel_launch(void* const* d_in, const int* in_sizes, int n_in,
                              void* d_out, int out_size, void* d_ws, size_t ws_size,
                              hipStream_t stream) {
  const int*   sent  = (const int*)d_in[0];
  const float* emb   = (const float*)d_in[1];
  const float* w_ih  = (const float*)d_in[2];
  const float* w_hh  = (const float*)d_in[3];
  const float* b_ih  = (const float*)d_in[4];
  const float* b_hh  = (const float*)d_in[5];
  const float* w_out = (const float*)d_in[6];
  const float* b_out = (const float*)d_in[7];
  float* out = (float*)d_out;

  // workspace layout
  unsigned long long* slots = (unsigned long long*)d_ws;         // 2*512*8 = 8 KB
  __hip_bfloat16* xg = (__hip_bfloat16*)((char*)d_ws + 16384);   // SEQ*NG bf16

  // zero slot tags (= h_0 state at epoch 0) every launch/replay
  hipMemsetAsync(d_ws, 0, 16384, stream);

  // xg GEMM
  dim3 ggrid(NG / BN, SEQ / BM);
  xg_gemm<<<ggrid, 256, 0, stream>>>(sent, emb, w_ih, b_ih, b_hh, xg);

  // persistent recurrence (64 WGs << 256 CUs -> always co-resident)
  lstm_rec<<<NWG, RT, 0, stream>>>(w_hh, xg, slots);

  // head: final h tagged 4096 lives in slots buffer 0
  head_kernel<<<1, 256, 0, stream>>>(slots, w_out, b_out, out);
}

// Round 6
// 7579.384 us; speedup vs baseline: 2.8647x; 1.0126x over previous
//
#include <hip/hip_runtime.h>
#include <hip/hip_bf16.h>

#define VOCAB 30522
#define EMB   768
#define HID   1024
#define SEQ   4096
#define NG    4096   // 4*HID gate rows
#define NWG   64     // workgroups in persistent recurrence kernel
#define RT    512    // threads per recurrence workgroup (8 waves)

static __device__ __forceinline__ unsigned short f32_to_bf16(float f) {
  unsigned u = __float_as_uint(f);
  u = (u + 0x7fffu + ((u >> 16) & 1u)) >> 16;   // round-to-nearest-even
  return (unsigned short)u;
}

// ---------------------------------------------------------------------------
// Kernel 1: xg[t][r] = dot(emb[sentence[t]], w_ih[r]) + b_ih[r] + b_hh[r]
// f32 tiled GEMM, output bf16. M=SEQ, N=NG, K=EMB.
// ---------------------------------------------------------------------------
#define BM 64
#define BN 64
#define BK 16

__global__ __launch_bounds__(256) void xg_gemm(
    const int* __restrict__ sent, const float* __restrict__ emb,
    const float* __restrict__ w_ih, const float* __restrict__ b_ih,
    const float* __restrict__ b_hh, __hip_bfloat16* __restrict__ xg) {
  __shared__ float As[BK][BM + 4];
  __shared__ float Bs[BK][BN + 4];
  const int tid = threadIdx.x;
  const int n0 = blockIdx.x * BN;
  const int m0 = blockIdx.y * BM;
  const int tx = tid & 15, ty = tid >> 4;       // 16 x 16 thread grid, 4x4 per thread
  const int lr = tid >> 2;                      // 0..63 tile row for loading
  const int lk = (tid & 3) * 4;                 // 0,4,8,12 k-offset for loading

  const int arow = sent[m0 + lr];
  const float* aptr = emb + (size_t)arow * EMB + lk;
  const float* bptr = w_ih + (size_t)(n0 + lr) * EMB + lk;

  float acc[4][4] = {};

  for (int k0 = 0; k0 < EMB; k0 += BK) {
    float4 av = *(const float4*)(aptr + k0);
    float4 bv = *(const float4*)(bptr + k0);
    __syncthreads();
    As[lk + 0][lr] = av.x; As[lk + 1][lr] = av.y;
    As[lk + 2][lr] = av.z; As[lk + 3][lr] = av.w;
    Bs[lk + 0][lr] = bv.x; Bs[lk + 1][lr] = bv.y;
    Bs[lk + 2][lr] = bv.z; Bs[lk + 3][lr] = bv.w;
    __syncthreads();
#pragma unroll
    for (int k = 0; k < BK; ++k) {
      float4 a = *(const float4*)&As[k][ty * 4];
      float4 b = *(const float4*)&Bs[k][tx * 4];
      acc[0][0] = fmaf(a.x, b.x, acc[0][0]); acc[0][1] = fmaf(a.x, b.y, acc[0][1]);
      acc[0][2] = fmaf(a.x, b.z, acc[0][2]); acc[0][3] = fmaf(a.x, b.w, acc[0][3]);
      acc[1][0] = fmaf(a.y, b.x, acc[1][0]); acc[1][1] = fmaf(a.y, b.y, acc[1][1]);
      acc[1][2] = fmaf(a.y, b.z, acc[1][2]); acc[1][3] = fmaf(a.y, b.w, acc[1][3]);
      acc[2][0] = fmaf(a.z, b.x, acc[2][0]); acc[2][1] = fmaf(a.z, b.y, acc[2][1]);
      acc[2][2] = fmaf(a.z, b.z, acc[2][2]); acc[2][3] = fmaf(a.z, b.w, acc[2][3]);
      acc[3][0] = fmaf(a.w, b.x, acc[3][0]); acc[3][1] = fmaf(a.w, b.y, acc[3][1]);
      acc[3][2] = fmaf(a.w, b.z, acc[3][2]); acc[3][3] = fmaf(a.w, b.w, acc[3][3]);
    }
  }

#pragma unroll
  for (int i = 0; i < 4; ++i) {
    int gm = m0 + ty * 4 + i;
#pragma unroll
    for (int j = 0; j < 4; ++j) {
      int gn = n0 + tx * 4 + j;
      float v = acc[i][j] + b_ih[gn] + b_hh[gn];
      xg[(size_t)gm * NG + gn] = __float2bfloat16(v);
    }
  }
}

// ---------------------------------------------------------------------------
// Kernel 2: persistent LSTM recurrence (round-5 structure + latency trims).
// 64 WGs x 512 threads. Wave wv owns h pair pw = wg*8+wv (h 2pw, 2pw+1),
// 8 gate rows s = 2q+m. Weights: 64 packed-bf16 u32 VGPRs/lane, asm-pinned.
// Sync: one 8B word per wave (tag32<<32 | bf16(h1)<<16 | bf16(h0)), relaxed
// agent atomics, double-buffered 512-word arrays; per-thread single-word
// 2-DEEP PIPELINED poll (check one in-flight load while the other issues).
// After reduce every lane L holds gate sum s=L&7 -> nonlinearity applied
// PER-LANE in parallel, then 3 parallel shuffles gather activated i/f/g/o.
// Race-free as before: tag t+2 cannot appear before every WG consumed tag t.
// ---------------------------------------------------------------------------
__global__ __launch_bounds__(RT, 1) void lstm_rec(
    const float* __restrict__ w_hh, const __hip_bfloat16* __restrict__ xg,
    unsigned long long* __restrict__ slots) {
  __shared__ unsigned hl[2][512];   // staged packed-bf16 h pairs (4 KB)

  const int tid  = threadIdx.x;
  const int wg   = blockIdx.x;
  const int lane = tid & 63;
  const int wv   = tid >> 6;     // wave 0..7
  const int c    = lane;         // column-pair chunk 0..63

  // --- one-time: load + pack this lane's 128 w_hh weights into 64 u32 ---
  unsigned wp[8][8];
#pragma unroll
  for (int s = 0; s < 8; ++s) {
    const int q = s >> 1, m = s & 1;
    const int gr = q * HID + wg * 16 + 2 * wv + m;
    const float* wr = w_hh + (size_t)gr * HID;
#pragma unroll
    for (int k = 0; k < 8; ++k) {
      float2 wv2 = *(const float2*)(wr + 2 * (c + 64 * k));
      wp[s][k] = ((unsigned)f32_to_bf16(wv2.y) << 16) | (unsigned)f32_to_bf16(wv2.x);
    }
  }
  // pin: opaque u32 values -> rematerialization impossible, spill unattractive
#pragma unroll
  for (int s = 0; s < 8; ++s)
#pragma unroll
    for (int k = 0; k < 8; ++k)
      asm volatile("" : "+v"(wp[s][k]));

  float cst = 0.f;               // cell state (valid on lanes 0,1; uniform code)
  const int m = lane & 1;        // which h of the pair this lane tracks

  for (int t = 0; t < SEQ; ++t) {
    // per-lane xg prefetch: lane L (<8) loads gate (L>>1), h-offset (L&1)
    float xqv = 0.f;
    if (lane < 8) {
      const int q = lane >> 1;
      xqv = __bfloat162float(
          xg[(size_t)t * NG + q * HID + wg * 16 + 2 * wv + (lane & 1)]);
    }

    // 2-deep pipelined poll of my single slot word (tag == t)
    const unsigned long long want = (unsigned long long)t;
    unsigned long long* sp = slots + ((t & 1) << 9) + tid;
    unsigned long long va = __hip_atomic_load(sp, __ATOMIC_RELAXED, __HIP_MEMORY_SCOPE_AGENT);
    unsigned long long vb = __hip_atomic_load(sp, __ATOMIC_RELAXED, __HIP_MEMORY_SCOPE_AGENT);
    unsigned long long v;
    for (;;) {
      if ((va >> 32) == want) { v = va; break; }
      va = __hip_atomic_load(sp, __ATOMIC_RELAXED, __HIP_MEMORY_SCOPE_AGENT);
      if ((vb >> 32) == want) { v = vb; break; }
      vb = __hip_atomic_load(sp, __ATOMIC_RELAXED, __HIP_MEMORY_SCOPE_AGENT);
    }
    hl[t & 1][tid] = (unsigned)v;
    __syncthreads();

    // unpack my h chunk once (8 words -> 16 f32), reuse for all 8 rows
    const unsigned* hb = hl[t & 1];
    float hx[8], hy[8];
#pragma unroll
    for (int k = 0; k < 8; ++k) {
      unsigned hw = hb[c + 64 * k];
      hx[k] = __uint_as_float(hw << 16);
      hy[k] = __uint_as_float(hw & 0xffff0000u);
    }

    float acc[8];
#pragma unroll
    for (int s = 0; s < 8; ++s) {
      float a = 0.f;
#pragma unroll
      for (int k = 0; k < 8; ++k) {
        unsigned w = wp[s][k];
        a = fmaf(__uint_as_float(w << 16),          hx[k], a);
        a = fmaf(__uint_as_float(w & 0xffff0000u),  hy[k], a);
      }
      acc[s] = a;
    }

    // folding tree: 8 partial sums x 64 lanes -> lane L holds S_{L&7}
#pragma unroll
    for (int M = 1, n = 8; M <= 4; M <<= 1, n >>= 1) {
#pragma unroll
      for (int j = 0; j < 4; ++j) {
        if (j < (n >> 1)) {
          float u  = (lane & M) ? acc[2 * j + 1] : acc[2 * j];
          float u2 = (lane & M) ? acc[2 * j]     : acc[2 * j + 1];
          acc[j] = u + __shfl_xor(u2, M, 64);
        }
      }
    }
    float r = acc[0];
    r += __shfl_xor(r, 8, 64);
    r += __shfl_xor(r, 16, 64);
    r += __shfl_xor(r, 32, 64);
    // r at lane L == full gate sum for s = L&7

    // per-lane nonlinearity (parallel): s=4,5 -> tanh via scaled sigmoid
    {
      const int s = lane & 7;
      const bool isg = (s >> 1) == 2;
      float z = r + xqv;
      z = isg ? 2.f * z : z;
      float sg = 1.f / (1.f + __expf(-z));
      r = isg ? fmaf(2.f, sg, -1.f) : sg;   // activated gate value
    }

    // gather activated gates for my h (m = lane&1): i=s(m), f=s(2+m), g=s(4+m), o=s(6+m)
    float i_ = __shfl(r, m,     64);
    float f_ = __shfl(r, 2 + m, 64);
    float g_ = __shfl(r, 4 + m, 64);
    float o_ = __shfl(r, 6 + m, 64);

    cst = fmaf(f_, cst, i_ * g_);
    // tanh(c) via scaled sigmoid: 2*sig(2c) - 1
    float th = fmaf(2.f, 1.f / (1.f + __expf(-2.f * cst)), -1.f);
    float hn = o_ * th;

    float hn1 = __shfl(hn, 1, 64);
    if (lane == 0) {
      unsigned payload = ((unsigned)f32_to_bf16(hn1) << 16) | (unsigned)f32_to_bf16(hn);
      unsigned long long pv =
          ((unsigned long long)(unsigned)(t + 1) << 32) | (unsigned long long)payload;
      __hip_atomic_store(slots + (((t + 1) & 1) << 9) + (wg * 8 + wv), pv,
                         __ATOMIC_RELAXED, __HIP_MEMORY_SCOPE_AGENT);
    }
    // no trailing barrier: next staging targets the other LDS buffer, and
    // tag t+2 cannot appear before every WG fully consumed tag t.
  }
}

// ---------------------------------------------------------------------------
// Kernel 3: y = h_T @ w_out.T + b_out ; log_softmax. h_T = slots buf0 packed.
// ---------------------------------------------------------------------------
__global__ __launch_bounds__(256) void head_kernel(
    const unsigned long long* __restrict__ hslots, const float* __restrict__ w_out,
    const float* __restrict__ b_out, float* __restrict__ out) {
  __shared__ float s0[256], s1[256];
  const int tid = threadIdx.x;
  float p0 = 0.f, p1 = 0.f;
  for (int w = tid; w < 512; w += 256) {
    unsigned pw = (unsigned)hslots[w];
    float h0 = __uint_as_float(pw << 16);
    float h1 = __uint_as_float(pw & 0xffff0000u);
    p0 = fmaf(h0, w_out[2 * w], fmaf(h1, w_out[2 * w + 1], p0));
    p1 = fmaf(h0, w_out[HID + 2 * w], fmaf(h1, w_out[HID + 2 * w + 1], p1));
  }
  s0[tid] = p0; s1[tid] = p1;
  __syncthreads();
  for (int off = 128; off; off >>= 1) {
    if (tid < off) { s0[tid] += s0[tid + off]; s1[tid] += s1[tid + off]; }
    __syncthreads();
  }
  if (tid == 0) {
    float y0 = s0[0] + b_out[0], y1 = s1[0] + b_out[1];
    float mx = fmaxf(y0, y1);
    float lse = mx + logf(expf(y0 - mx) + expf(y1 - mx));
    out[0] = y0 - lse;
    out[1] = y1 - lse;
  }
}

// ---------------------------------------------------------------------------
extern "C" void kernel_launch(void* const* d_in, const int* in_sizes, int n_in,
                              void* d_out, int out_size, void* d_ws, size_t ws_size,
                              hipStream_t stream) {
  const int*   sent  = (const int*)d_in[0];
  const float* emb   = (const float*)d_in[1];
  const float* w_ih  = (const float*)d_in[2];
  const float* w_hh  = (const float*)d_in[3];
  const float* b_ih  = (const float*)d_in[4];
  const float* b_hh  = (const float*)d_in[5];
  const float* w_out = (const float*)d_in[6];
  const float* b_out = (const float*)d_in[7];
  float* out = (float*)d_out;

  // workspace layout
  unsigned long long* slots = (unsigned long long*)d_ws;         // 2*512*8 = 8 KB
  __hip_bfloat16* xg = (__hip_bfloat16*)((char*)d_ws + 16384);   // SEQ*NG bf16

  // zero slot tags (= h_0 state at epoch 0) every launch/replay
  hipMemsetAsync(d_ws, 0, 16384, stream);

  // xg GEMM
  dim3 ggrid(NG / BN, SEQ / BM);
  xg_gemm<<<ggrid, 256, 0, stream>>>(sent, emb, w_ih, b_ih, b_hh, xg);

  // persistent recurrence (64 WGs << 256 CUs -> always co-resident)
  lstm_rec<<<NWG, RT, 0, stream>>>(w_hh, xg, slots);

  // head: final h tagged 4096 lives in slots buffer 0
  head_kernel<<<1, 256, 0, stream>>>(slots, w_out, b_out, out);
}

// Round 7
// 7479.873 us; speedup vs baseline: 2.9028x; 1.0133x over previous
//
#include <hip/hip_runtime.h>
#include <hip/hip_bf16.h>

#define VOCAB 30522
#define EMB   768
#define HID   1024
#define SEQ   4096
#define NG    4096   // 4*HID gate rows
#define NWG   128    // workgroups in persistent recurrence kernel
#define RT    256    // threads per recurrence workgroup (4 waves = 1/SIMD)

static __device__ __forceinline__ unsigned short f32_to_bf16(float f) {
  unsigned u = __float_as_uint(f);
  u = (u + 0x7fffu + ((u >> 16) & 1u)) >> 16;   // round-to-nearest-even
  return (unsigned short)u;
}

// ---------------------------------------------------------------------------
// Kernel 1: xg[t][r] = dot(emb[sentence[t]], w_ih[r]) + b_ih[r] + b_hh[r]
// f32 tiled GEMM, output bf16. M=SEQ, N=NG, K=EMB.
// ---------------------------------------------------------------------------
#define BM 64
#define BN 64
#define BK 16

__global__ __launch_bounds__(256) void xg_gemm(
    const int* __restrict__ sent, const float* __restrict__ emb,
    const float* __restrict__ w_ih, const float* __restrict__ b_ih,
    const float* __restrict__ b_hh, __hip_bfloat16* __restrict__ xg) {
  __shared__ float As[BK][BM + 4];
  __shared__ float Bs[BK][BN + 4];
  const int tid = threadIdx.x;
  const int n0 = blockIdx.x * BN;
  const int m0 = blockIdx.y * BM;
  const int tx = tid & 15, ty = tid >> 4;       // 16 x 16 thread grid, 4x4 per thread
  const int lr = tid >> 2;                      // 0..63 tile row for loading
  const int lk = (tid & 3) * 4;                 // 0,4,8,12 k-offset for loading

  const int arow = sent[m0 + lr];
  const float* aptr = emb + (size_t)arow * EMB + lk;
  const float* bptr = w_ih + (size_t)(n0 + lr) * EMB + lk;

  float acc[4][4] = {};

  for (int k0 = 0; k0 < EMB; k0 += BK) {
    float4 av = *(const float4*)(aptr + k0);
    float4 bv = *(const float4*)(bptr + k0);
    __syncthreads();
    As[lk + 0][lr] = av.x; As[lk + 1][lr] = av.y;
    As[lk + 2][lr] = av.z; As[lk + 3][lr] = av.w;
    Bs[lk + 0][lr] = bv.x; Bs[lk + 1][lr] = bv.y;
    Bs[lk + 2][lr] = bv.z; Bs[lk + 3][lr] = bv.w;
    __syncthreads();
#pragma unroll
    for (int k = 0; k < BK; ++k) {
      float4 a = *(const float4*)&As[k][ty * 4];
      float4 b = *(const float4*)&Bs[k][tx * 4];
      acc[0][0] = fmaf(a.x, b.x, acc[0][0]); acc[0][1] = fmaf(a.x, b.y, acc[0][1]);
      acc[0][2] = fmaf(a.x, b.z, acc[0][2]); acc[0][3] = fmaf(a.x, b.w, acc[0][3]);
      acc[1][0] = fmaf(a.y, b.x, acc[1][0]); acc[1][1] = fmaf(a.y, b.y, acc[1][1]);
      acc[1][2] = fmaf(a.y, b.z, acc[1][2]); acc[1][3] = fmaf(a.y, b.w, acc[1][3]);
      acc[2][0] = fmaf(a.z, b.x, acc[2][0]); acc[2][1] = fmaf(a.z, b.y, acc[2][1]);
      acc[2][2] = fmaf(a.z, b.z, acc[2][2]); acc[2][3] = fmaf(a.z, b.w, acc[2][3]);
      acc[3][0] = fmaf(a.w, b.x, acc[3][0]); acc[3][1] = fmaf(a.w, b.y, acc[3][1]);
      acc[3][2] = fmaf(a.w, b.z, acc[3][2]); acc[3][3] = fmaf(a.w, b.w, acc[3][3]);
    }
  }

#pragma unroll
  for (int i = 0; i < 4; ++i) {
    int gm = m0 + ty * 4 + i;
#pragma unroll
    for (int j = 0; j < 4; ++j) {
      int gn = n0 + tx * 4 + j;
      float v = acc[i][j] + b_ih[gn] + b_hh[gn];
      xg[(size_t)gm * NG + gn] = __float2bfloat16(v);
    }
  }
}

// ---------------------------------------------------------------------------
// Kernel 2: persistent LSTM recurrence.
// 128 WGs x 256 threads (4 waves = 1 wave/SIMD: dot phase has no SIMD
// sharing, halving its wall time vs 8-wave config). Wave wv owns h pair
// pw = wg*4 + wv (h indices 2pw, 2pw+1) and its 8 gate rows s = 2q+m.
// Weights: 128 f32 (bit-cast u32) VGPRs per lane, asm-pinned with the
// round-5/6-proven u32 pattern; __uint_as_float is free -> dot has ZERO
// unpack ops for weights (was 128 VALU ops/step/wave).
// Sync (unchanged, proven): one 8B word per wave (tag32<<32 | bf16(h1)<<16
// | bf16(h0)), relaxed agent atomics, double-buffered 512-word arrays;
// each thread polls 2 words, stages payloads to LDS, one barrier.
// Race-free: tag t+2 cannot appear before every WG fully consumed tag t.
// ---------------------------------------------------------------------------
__global__ __launch_bounds__(RT, 1) void lstm_rec(
    const float* __restrict__ w_hh, const __hip_bfloat16* __restrict__ xg,
    unsigned long long* __restrict__ slots) {
  __shared__ unsigned hl[2][512];   // staged packed-bf16 h pairs (4 KB)

  const int tid  = threadIdx.x;
  const int wg   = blockIdx.x;
  const int lane = tid & 63;
  const int wv   = tid >> 6;     // wave 0..3
  const int c    = lane;         // column-pair chunk 0..63
  const int m    = lane & 1;     // which h of the pair this lane tracks

  // --- one-time: load this lane's 128 f32 w_hh weights, bit-cast to u32 ---
  // row s = 2q+m -> gate q, h-offset m; cols: pairs p = c + 64k, k=0..7
  unsigned wu[8][16];
#pragma unroll
  for (int s = 0; s < 8; ++s) {
    const int q = s >> 1, mm = s & 1;
    const int gr = q * HID + wg * 8 + 2 * wv + mm;
    const float* wr = w_hh + (size_t)gr * HID;
#pragma unroll
    for (int k = 0; k < 8; ++k) {
      float2 wv2 = *(const float2*)(wr + 2 * (c + 64 * k));
      wu[s][2 * k]     = __float_as_uint(wv2.x);
      wu[s][2 * k + 1] = __float_as_uint(wv2.y);
    }
  }
  // pin: opaque u32 values (proven pattern) -> no remat, no spill
#pragma unroll
  for (int s = 0; s < 8; ++s)
#pragma unroll
    for (int k = 0; k < 16; ++k)
      asm volatile("" : "+v"(wu[s][k]));

  float cst = 0.f;               // cell state (valid on lanes 0,1; uniform code)

  for (int t = 0; t < SEQ; ++t) {
    // per-lane xg prefetch: lane L (<8) loads gate (L>>1), h-offset (L&1)
    float xqv = 0.f;
    if (lane < 8) {
      const int q = lane >> 1;
      xqv = __bfloat162float(
          xg[(size_t)t * NG + q * HID + wg * 8 + 2 * wv + (lane & 1)]);
    }

    // poll my 2 slot words until both carry tag == t
    const unsigned long long want = (unsigned long long)t;
    unsigned long long* sp = slots + ((t & 1) << 9) + 2 * tid;
    unsigned long long v0, v1;
    for (;;) {
      v0 = __hip_atomic_load(sp,     __ATOMIC_RELAXED, __HIP_MEMORY_SCOPE_AGENT);
      v1 = __hip_atomic_load(sp + 1, __ATOMIC_RELAXED, __HIP_MEMORY_SCOPE_AGENT);
      if (((v0 >> 32) == want) & ((v1 >> 32) == want)) break;
    }
    hl[t & 1][2 * tid]     = (unsigned)v0;
    hl[t & 1][2 * tid + 1] = (unsigned)v1;
    __syncthreads();

    // unpack my h chunk once (8 words -> 16 f32), reuse for all 8 rows
    const unsigned* hb = hl[t & 1];
    float hx[8], hy[8];
#pragma unroll
    for (int k = 0; k < 8; ++k) {
      unsigned hw = hb[c + 64 * k];
      hx[k] = __uint_as_float(hw << 16);
      hy[k] = __uint_as_float(hw & 0xffff0000u);
    }

    float acc[8];
#pragma unroll
    for (int s = 0; s < 8; ++s) {
      float a = 0.f;
#pragma unroll
      for (int k = 0; k < 8; ++k) {
        a = fmaf(__uint_as_float(wu[s][2 * k]),     hx[k], a);
        a = fmaf(__uint_as_float(wu[s][2 * k + 1]), hy[k], a);
      }
      acc[s] = a;
    }

    // folding tree: 8 partial sums x 64 lanes -> lane L holds S_{L&7}
#pragma unroll
    for (int M = 1, n = 8; M <= 4; M <<= 1, n >>= 1) {
#pragma unroll
      for (int j = 0; j < 4; ++j) {
        if (j < (n >> 1)) {
          float u  = (lane & M) ? acc[2 * j + 1] : acc[2 * j];
          float u2 = (lane & M) ? acc[2 * j]     : acc[2 * j + 1];
          acc[j] = u + __shfl_xor(u2, M, 64);
        }
      }
    }
    float r = acc[0];
    r += __shfl_xor(r, 8, 64);
    r += __shfl_xor(r, 16, 64);
    r += __shfl_xor(r, 32, 64);
    // r at lane L == full gate sum for s = L&7

    // per-lane nonlinearity (parallel): s=4,5 -> tanh via scaled sigmoid
    {
      const int s = lane & 7;
      const bool isg = (s >> 1) == 2;
      float z = r + xqv;
      z = isg ? 2.f * z : z;
      float sg = 1.f / (1.f + __expf(-z));
      r = isg ? fmaf(2.f, sg, -1.f) : sg;   // activated gate value
    }

    // gather activated gates for my h (m = lane&1): i=s(m), f=s(2+m), g=s(4+m), o=s(6+m)
    float i_ = __shfl(r, m,     64);
    float f_ = __shfl(r, 2 + m, 64);
    float g_ = __shfl(r, 4 + m, 64);
    float o_ = __shfl(r, 6 + m, 64);

    cst = fmaf(f_, cst, i_ * g_);
    // tanh(c) via scaled sigmoid: 2*sig(2c) - 1
    float th = fmaf(2.f, 1.f / (1.f + __expf(-2.f * cst)), -1.f);
    float hn = o_ * th;

    float hn1 = __shfl(hn, 1, 64);
    if (lane == 0) {
      unsigned payload = ((unsigned)f32_to_bf16(hn1) << 16) | (unsigned)f32_to_bf16(hn);
      unsigned long long pv =
          ((unsigned long long)(unsigned)(t + 1) << 32) | (unsigned long long)payload;
      __hip_atomic_store(slots + (((t + 1) & 1) << 9) + (wg * 4 + wv), pv,
                         __ATOMIC_RELAXED, __HIP_MEMORY_SCOPE_AGENT);
    }
    // no trailing barrier: next staging targets the other LDS buffer, and
    // tag t+2 cannot appear before every WG fully consumed tag t.
  }
}

// ---------------------------------------------------------------------------
// Kernel 3: y = h_T @ w_out.T + b_out ; log_softmax. h_T = slots buf0 packed.
// ---------------------------------------------------------------------------
__global__ __launch_bounds__(256) void head_kernel(
    const unsigned long long* __restrict__ hslots, const float* __restrict__ w_out,
    const float* __restrict__ b_out, float* __restrict__ out) {
  __shared__ float s0[256], s1[256];
  const int tid = threadIdx.x;
  float p0 = 0.f, p1 = 0.f;
  for (int w = tid; w < 512; w += 256) {
    unsigned pw = (unsigned)hslots[w];
    float h0 = __uint_as_float(pw << 16);
    float h1 = __uint_as_float(pw & 0xffff0000u);
    p0 = fmaf(h0, w_out[2 * w], fmaf(h1, w_out[2 * w + 1], p0));
    p1 = fmaf(h0, w_out[HID + 2 * w], fmaf(h1, w_out[HID + 2 * w + 1], p1));
  }
  s0[tid] = p0; s1[tid] = p1;
  __syncthreads();
  for (int off = 128; off; off >>= 1) {
    if (tid < off) { s0[tid] += s0[tid + off]; s1[tid] += s1[tid + off]; }
    __syncthreads();
  }
  if (tid == 0) {
    float y0 = s0[0] + b_out[0], y1 = s1[0] + b_out[1];
    float mx = fmaxf(y0, y1);
    float lse = mx + logf(expf(y0 - mx) + expf(y1 - mx));
    out[0] = y0 - lse;
    out[1] = y1 - lse;
  }
}

// ---------------------------------------------------------------------------
extern "C" void kernel_launch(void* const* d_in, const int* in_sizes, int n_in,
                              void* d_out, int out_size, void* d_ws, size_t ws_size,
                              hipStream_t stream) {
  const int*   sent  = (const int*)d_in[0];
  const float* emb   = (const float*)d_in[1];
  const float* w_ih  = (const float*)d_in[2];
  const float* w_hh  = (const float*)d_in[3];
  const float* b_ih  = (const float*)d_in[4];
  const float* b_hh  = (const float*)d_in[5];
  const float* w_out = (const float*)d_in[6];
  const float* b_out = (const float*)d_in[7];
  float* out = (float*)d_out;

  // workspace layout
  unsigned long long* slots = (unsigned long long*)d_ws;         // 2*512*8 = 8 KB
  __hip_bfloat16* xg = (__hip_bfloat16*)((char*)d_ws + 16384);   // SEQ*NG bf16

  // zero slot tags (= h_0 state at epoch 0) every launch/replay
  hipMemsetAsync(d_ws, 0, 16384, stream);

  // xg GEMM
  dim3 ggrid(NG / BN, SEQ / BM);
  xg_gemm<<<ggrid, 256, 0, stream>>>(sent, emb, w_ih, b_ih, b_hh, xg);

  // persistent recurrence (128 WGs << 256 CUs -> always co-resident)
  lstm_rec<<<NWG, RT, 0, stream>>>(w_hh, xg, slots);

  // head: final h tagged 4096 lives in slots buffer 0
  head_kernel<<<1, 256, 0, stream>>>(slots, w_out, b_out, out);
}